// Round 2
// baseline (1033.047 us; speedup 1.0000x reference)
//
#include <hip/hip_runtime.h>
#include <math.h>
#include <float.h>

#define BLK 256
#define MAIN_BLOCKS 2048
#define EXP_BLOCKS 2048

// ---------------------------------------------------------------------------
// K0: exclusive prefix scan of the two ragged-count arrays (single block).
// dag_starts[0..nd], obs_starts[0..no] (last entry = total).
// ---------------------------------------------------------------------------
__global__ __launch_bounds__(1024) void scan2_kernel(
    const int* __restrict__ dag_cnt, int nd,
    const int* __restrict__ obs_cnt, int no,
    int* __restrict__ dag_starts, int* __restrict__ obs_starts)
{
    __shared__ int buf[1024];
    const int t = threadIdx.x;

    // --- dag counts ---
    int carry = 0;
    for (int base = 0; base < nd; base += 1024) {
        int idx = base + t;
        int v = (idx < nd) ? dag_cnt[idx] : 0;
        buf[t] = v;
        __syncthreads();
        int xv = v;
        for (int off = 1; off < 1024; off <<= 1) {
            int y = (t >= off) ? buf[t - off] : 0;
            __syncthreads();
            xv += y;
            buf[t] = xv;
            __syncthreads();
        }
        if (idx < nd) dag_starts[idx] = carry + xv - v;  // exclusive
        int tot = buf[1023];
        __syncthreads();
        carry += tot;
    }
    if (t == 0) dag_starts[nd] = carry;

    // --- obs counts ---
    carry = 0;
    for (int base = 0; base < no; base += 1024) {
        int idx = base + t;
        int v = (idx < no) ? obs_cnt[idx] : 0;
        buf[t] = v;
        __syncthreads();
        int xv = v;
        for (int off = 1; off < 1024; off <<= 1) {
            int y = (t >= off) ? buf[t - off] : 0;
            __syncthreads();
            xv += y;
            buf[t] = xv;
            __syncthreads();
        }
        if (idx < no) obs_starts[idx] = carry + xv - v;
        int tot = buf[1023];
        __syncthreads();
        carry += tot;
    }
    if (t == 0) obs_starts[no] = carry;
}

// ---------------------------------------------------------------------------
// K_pre: per-segment layer-1 partials: out[seg][j] = sum_k summ[seg][k]*W1[row_off+k][j]
// (+ b1[j] when add_bias). Shared across all nodes of the segment.
// ---------------------------------------------------------------------------
__global__ __launch_bounds__(256) void seg_h1_kernel(
    const float* __restrict__ summ, int nseg,
    const float* __restrict__ W1, int row_off,
    const float* __restrict__ b1, int add_bias,
    float* __restrict__ outp)
{
    __shared__ float Wl[32 * 32];
    for (int t = threadIdx.x; t < 32 * 32; t += blockDim.x)
        Wl[t] = W1[(size_t)(row_off + t / 32) * 32 + (t % 32)];
    __syncthreads();

    int gid = blockIdx.x * blockDim.x + threadIdx.x;
    int seg = gid / 32;
    int j   = gid % 32;
    if (seg >= nseg) return;

    const float* srow = summ + (size_t)seg * 32;
    float acc = add_bias ? b1[j] : 0.f;
#pragma unroll
    for (int k = 0; k < 32; k++)
        acc = fmaf(srow[k], Wl[k * 32 + j], acc);
    outp[(size_t)seg * 32 + j] = acc;
}

// ---------------------------------------------------------------------------
// K1: main MLP + score + per-block max.
// ---------------------------------------------------------------------------
__global__ __launch_bounds__(BLK) void mlp_score_kernel(
    const float* __restrict__ x, const float* __restrict__ emb,
    const float* __restrict__ dag_h1, const float* __restrict__ glob_h1,
    const int* __restrict__ dag_starts, int nd,
    const int* __restrict__ obs_starts, int no,
    const int* __restrict__ mask,
    const float* __restrict__ W1, const float* __restrict__ W2,
    const float* __restrict__ b2, const float* __restrict__ W3,
    const float* __restrict__ b3, const float* __restrict__ W4,
    const float* __restrict__ b4,
    float* __restrict__ scores, float* __restrict__ block_max, int N)
{
    __shared__ float W1l[37 * 32];
    __shared__ float W2l[32 * 16];
    __shared__ float W3l[16 * 8];
    __shared__ float W4l[8];
    __shared__ float b2l[16];
    __shared__ float b3l[8];
    __shared__ float b4s;

    for (int t = threadIdx.x; t < 37 * 32; t += BLK) W1l[t] = W1[t];
    for (int t = threadIdx.x; t < 32 * 16; t += BLK) W2l[t] = W2[t];
    for (int t = threadIdx.x; t < 16 * 8;  t += BLK) W3l[t] = W3[t];
    if (threadIdx.x < 8)  W4l[threadIdx.x] = W4[threadIdx.x];
    if (threadIdx.x < 16) b2l[threadIdx.x] = b2[threadIdx.x];
    if (threadIdx.x < 8)  b3l[threadIdx.x] = b3[threadIdx.x];
    if (threadIdx.x == 0) b4s = b4[0];
    __syncthreads();

    float lmax = -INFINITY;
    const int stride = gridDim.x * BLK;

    for (int i = blockIdx.x * BLK + threadIdx.x; i < N; i += stride) {
        // --- segment lookup via binary search on exclusive-scan boundaries ---
        int lo = 0, hi = nd;
        while (hi - lo > 1) {
            int mid = (lo + hi) >> 1;
            if (dag_starts[mid] <= i) lo = mid; else hi = mid;
        }
        const int d = lo;
        lo = 0; hi = no;
        while (hi - lo > 1) {
            int mid = (lo + hi) >> 1;
            if (obs_starts[mid] <= i) lo = mid; else hi = mid;
        }
        const int o = lo;

        // --- layer 1: init from precomputed dag/glob partials (b1 folded in) ---
        float h1[32];
        const float4* dh = (const float4*)(dag_h1 + (size_t)d * 32);
        const float4* gh = (const float4*)(glob_h1 + (size_t)o * 32);
#pragma unroll
        for (int q = 0; q < 8; q++) {
            float4 a = dh[q], b = gh[q];
            h1[4 * q + 0] = a.x + b.x;
            h1[4 * q + 1] = a.y + b.y;
            h1[4 * q + 2] = a.z + b.z;
            h1[4 * q + 3] = a.w + b.w;
        }

        const float* xr = x + (size_t)i * 5;
#pragma unroll
        for (int k = 0; k < 5; k++) {
            float v = xr[k];
#pragma unroll
            for (int j = 0; j < 32; j++)
                h1[j] = fmaf(v, W1l[k * 32 + j], h1[j]);
        }

        const float4* er = (const float4*)(emb + (size_t)i * 32);
#pragma unroll
        for (int q = 0; q < 8; q++) {
            float4 e = er[q];
            float ev[4] = { e.x, e.y, e.z, e.w };
#pragma unroll
            for (int kk = 0; kk < 4; kk++) {
                float v = ev[kk];
                const int k = 5 + q * 4 + kk;
#pragma unroll
                for (int j = 0; j < 32; j++)
                    h1[j] = fmaf(v, W1l[k * 32 + j], h1[j]);
            }
        }
#pragma unroll
        for (int j = 0; j < 32; j++) h1[j] = fmaxf(h1[j], 0.f);

        // --- layer 2 ---
        float h2[16];
#pragma unroll
        for (int j = 0; j < 16; j++) h2[j] = b2l[j];
#pragma unroll
        for (int k = 0; k < 32; k++) {
            float v = h1[k];
#pragma unroll
            for (int j = 0; j < 16; j++)
                h2[j] = fmaf(v, W2l[k * 16 + j], h2[j]);
        }
#pragma unroll
        for (int j = 0; j < 16; j++) h2[j] = fmaxf(h2[j], 0.f);

        // --- layer 3 ---
        float h3[8];
#pragma unroll
        for (int j = 0; j < 8; j++) h3[j] = b3l[j];
#pragma unroll
        for (int k = 0; k < 16; k++) {
            float v = h2[k];
#pragma unroll
            for (int j = 0; j < 8; j++)
                h3[j] = fmaf(v, W3l[k * 8 + j], h3[j]);
        }
#pragma unroll
        for (int j = 0; j < 8; j++) h3[j] = fmaxf(h3[j], 0.f);

        // --- layer 4 ---
        float s = b4s;
#pragma unroll
        for (int k = 0; k < 8; k++) s = fmaf(h3[k], W4l[k], s);

        s = (mask[i] != 0) ? s : -FLT_MAX;
        scores[i] = s;
        lmax = fmaxf(lmax, s);
    }

    // --- block max reduction ---
    __shared__ float red[BLK];
    red[threadIdx.x] = lmax;
    __syncthreads();
    for (int off = BLK / 2; off > 0; off >>= 1) {
        if (threadIdx.x < off)
            red[threadIdx.x] = fmaxf(red[threadIdx.x], red[threadIdx.x + off]);
        __syncthreads();
    }
    if (threadIdx.x == 0) block_max[blockIdx.x] = red[0];
}

// ---------------------------------------------------------------------------
// K2: reduce block maxes (single block).
// ---------------------------------------------------------------------------
__global__ __launch_bounds__(1024) void max_reduce_kernel(
    const float* __restrict__ bm, int n, float* __restrict__ gmax)
{
    __shared__ float red[1024];
    float m = -INFINITY;
    for (int i = threadIdx.x; i < n; i += 1024) m = fmaxf(m, bm[i]);
    red[threadIdx.x] = m;
    __syncthreads();
    for (int off = 512; off > 0; off >>= 1) {
        if (threadIdx.x < off)
            red[threadIdx.x] = fmaxf(red[threadIdx.x], red[threadIdx.x + off]);
        __syncthreads();
    }
    if (threadIdx.x == 0) *gmax = red[0];
}

// ---------------------------------------------------------------------------
// K3: per-block partial sums of exp(s - gmax) in f64.
// ---------------------------------------------------------------------------
__global__ __launch_bounds__(BLK) void expsum_kernel(
    const float* __restrict__ scores, int N,
    const float* __restrict__ gmaxp, double* __restrict__ bsum)
{
    const float gm = *gmaxp;
    double s = 0.0;
    const int stride = gridDim.x * BLK;
    for (int i = blockIdx.x * BLK + threadIdx.x; i < N; i += stride)
        s += (double)expf(scores[i] - gm);   // masked (-FLT_MAX) -> expf -> 0

    __shared__ double red[BLK];
    red[threadIdx.x] = s;
    __syncthreads();
    for (int off = BLK / 2; off > 0; off >>= 1) {
        if (threadIdx.x < off)
            red[threadIdx.x] += red[threadIdx.x + off];
        __syncthreads();
    }
    if (threadIdx.x == 0) bsum[blockIdx.x] = red[0];
}

// ---------------------------------------------------------------------------
// K4: reduce partial sums (single block, f64).
// ---------------------------------------------------------------------------
__global__ __launch_bounds__(1024) void sum_reduce_kernel(
    const double* __restrict__ bs, int n, double* __restrict__ Z)
{
    __shared__ double red[1024];
    double s = 0.0;
    for (int i = threadIdx.x; i < n; i += 1024) s += bs[i];
    red[threadIdx.x] = s;
    __syncthreads();
    for (int off = 512; off > 0; off >>= 1) {
        if (threadIdx.x < off)
            red[threadIdx.x] += red[threadIdx.x + off];
        __syncthreads();
    }
    if (threadIdx.x == 0) *Z = red[0];
}

// ---------------------------------------------------------------------------
// K5: finalize out[i] = exp(s - gmax) / Z  (masked -> exactly 0).
// ---------------------------------------------------------------------------
__global__ __launch_bounds__(BLK) void finalize_kernel(
    const float* __restrict__ scores, int N,
    const float* __restrict__ gmaxp, const double* __restrict__ Zp,
    float* __restrict__ outp)
{
    const float gm = *gmaxp;
    const float rZ = (float)(1.0 / *Zp);
    int i = blockIdx.x * BLK + threadIdx.x;
    if (i < N) outp[i] = expf(scores[i] - gm) * rZ;
}

// ---------------------------------------------------------------------------
extern "C" void kernel_launch(void* const* d_in, const int* in_sizes, int n_in,
                              void* d_out, int out_size, void* d_ws, size_t ws_size,
                              hipStream_t stream)
{
    const float* x        = (const float*)d_in[0];
    const float* emb      = (const float*)d_in[1];
    const float* dag_sum  = (const float*)d_in[2];
    const float* glob_sum = (const float*)d_in[3];
    const int*   dag_cnt  = (const int*)d_in[4];
    const int*   obs_cnt  = (const int*)d_in[5];
    const int*   mask     = (const int*)d_in[6];   // bool staged as int32
    const float* W1 = (const float*)d_in[7];
    const float* b1 = (const float*)d_in[8];
    const float* W2 = (const float*)d_in[9];
    const float* b2 = (const float*)d_in[10];
    const float* W3 = (const float*)d_in[11];
    const float* b3 = (const float*)d_in[12];
    const float* W4 = (const float*)d_in[13];
    const float* b4 = (const float*)d_in[14];
    float* outp = (float*)d_out;

    const int N  = in_sizes[0] / 5;   // 2,000,000
    const int nd = in_sizes[4];       // 20,000
    const int no = in_sizes[5];       // 1,000

    // --- workspace layout (16B aligned slices) ---
    char* ws = (char*)d_ws;
    size_t off = 0;
    auto alloc = [&](size_t bytes) {
        void* p = ws + off;
        off += (bytes + 15) & ~(size_t)15;
        return p;
    };
    int*    dag_starts = (int*)   alloc((size_t)(nd + 1) * sizeof(int));
    int*    obs_starts = (int*)   alloc((size_t)(no + 1) * sizeof(int));
    float*  dag_h1     = (float*) alloc((size_t)nd * 32 * sizeof(float));
    float*  glob_h1    = (float*) alloc((size_t)no * 32 * sizeof(float));
    float*  scores     = (float*) alloc((size_t)N * sizeof(float));
    float*  block_max  = (float*) alloc((size_t)MAIN_BLOCKS * sizeof(float));
    double* block_sum  = (double*)alloc((size_t)EXP_BLOCKS * sizeof(double));
    float*  gmax       = (float*) alloc(sizeof(float));
    double* Z          = (double*)alloc(sizeof(double));
    (void)ws_size;

    // K0: prefix scans
    scan2_kernel<<<1, 1024, 0, stream>>>(dag_cnt, nd, obs_cnt, no, dag_starts, obs_starts);

    // K_pre: per-segment layer-1 partials (W1 rows 37..68 = dag, 69..100 = glob+b1)
    {
        int blocks = (nd * 32 + 255) / 256;
        seg_h1_kernel<<<blocks, 256, 0, stream>>>(dag_sum, nd, W1, 37, b1, 0, dag_h1);
        blocks = (no * 32 + 255) / 256;
        seg_h1_kernel<<<blocks, 256, 0, stream>>>(glob_sum, no, W1, 69, b1, 1, glob_h1);
    }

    // K1: main MLP + scores + block maxes
    mlp_score_kernel<<<MAIN_BLOCKS, BLK, 0, stream>>>(
        x, emb, dag_h1, glob_h1, dag_starts, nd, obs_starts, no, mask,
        W1, W2, b2, W3, b3, W4, b4, scores, block_max, N);

    // K2: global max
    max_reduce_kernel<<<1, 1024, 0, stream>>>(block_max, MAIN_BLOCKS, gmax);

    // K3: exp partial sums
    expsum_kernel<<<EXP_BLOCKS, BLK, 0, stream>>>(scores, N, gmax, block_sum);

    // K4: total Z
    sum_reduce_kernel<<<1, 1024, 0, stream>>>(block_sum, EXP_BLOCKS, Z);

    // K5: finalize
    finalize_kernel<<<(N + BLK - 1) / BLK, BLK, 0, stream>>>(scores, N, gmax, Z, outp);
}

// Round 3
// 930.659 us; speedup vs baseline: 1.1100x; 1.1100x over previous
//
#include <hip/hip_runtime.h>
#include <math.h>
#include <float.h>

#define BLK 256
#define MAIN_BLOCKS 2048

// ---------------------------------------------------------------------------
// K0: fast exclusive scan of both count arrays. One block, 1024 threads.
// Each thread owns a contiguous chunk; one shuffle-based block scan.
// ---------------------------------------------------------------------------
__device__ __forceinline__ void scan_one(const int* __restrict__ cnt, int n,
                                         int* __restrict__ starts, int* wsum)
{
    const int t = threadIdx.x;
    const int chunk = (n + 1023) / 1024;
    const int base = t * chunk;

    int sum = 0;
    for (int k = 0; k < chunk; k++) {
        int idx = base + k;
        if (idx < n) sum += cnt[idx];
    }

    // inclusive wave scan
    const int lane = t & 63, wid = t >> 6;
    int v = sum;
#pragma unroll
    for (int off = 1; off < 64; off <<= 1) {
        int y = __shfl_up(v, off);
        if (lane >= off) v += y;
    }
    if (lane == 63) wsum[wid] = v;
    __syncthreads();
    if (wid == 0) {
        int w = (lane < 16) ? wsum[lane] : 0;
#pragma unroll
        for (int off = 1; off < 16; off <<= 1) {
            int y = __shfl_up(w, off);
            if (lane >= off) w += y;
        }
        if (lane < 16) wsum[lane] = w;  // inclusive wave totals
    }
    __syncthreads();

    int thr_excl = ((wid > 0) ? wsum[wid - 1] : 0) + v - sum;
    int run = thr_excl;
    for (int k = 0; k < chunk; k++) {
        int idx = base + k;
        if (idx < n) { starts[idx] = run; run += cnt[idx]; }
    }
    if (t == 0) starts[n] = wsum[15];
    __syncthreads();   // protect wsum reuse
}

__global__ __launch_bounds__(1024) void scan2_kernel(
    const int* __restrict__ dag_cnt, int nd,
    const int* __restrict__ obs_cnt, int no,
    int* __restrict__ dag_starts, int* __restrict__ obs_starts)
{
    __shared__ int wsum[16];
    scan_one(dag_cnt, nd, dag_starts, wsum);
    scan_one(obs_cnt, no, obs_starts, wsum);
}

// ---------------------------------------------------------------------------
// K1: expand segment ids to per-node arrays (one block per segment).
// ---------------------------------------------------------------------------
__global__ __launch_bounds__(128) void expand_ids_kernel(
    const int* __restrict__ dag_starts, int nd,
    const int* __restrict__ obs_starts, int no,
    int* __restrict__ dag_ids, int* __restrict__ obs_ids)
{
    int seg = blockIdx.x;
    if (seg < nd) {
        int s = dag_starts[seg], e = dag_starts[seg + 1];
        for (int i = s + threadIdx.x; i < e; i += 128) dag_ids[i] = seg;
    } else {
        int g = seg - nd;
        int s = obs_starts[g], e = obs_starts[g + 1];
        for (int i = s + threadIdx.x; i < e; i += 128) obs_ids[i] = g;
    }
}

// ---------------------------------------------------------------------------
// K2: per-segment layer-1 partials for dag (rows 37..68, no bias) and
// glob (rows 69..100, +b1) in one launch.
// ---------------------------------------------------------------------------
__global__ __launch_bounds__(256) void seg_h1_kernel(
    const float* __restrict__ dag_sum, int nd,
    const float* __restrict__ glob_sum, int no,
    const float* __restrict__ W1, const float* __restrict__ b1,
    float* __restrict__ dag_h1, float* __restrict__ glob_h1)
{
    __shared__ float Wd[32 * 32];
    __shared__ float Wg[32 * 32];
    for (int t = threadIdx.x; t < 32 * 32; t += 256) {
        int k = t / 32, j = t % 32;
        Wd[t] = W1[(size_t)(37 + k) * 32 + j];
        Wg[t] = W1[(size_t)(69 + k) * 32 + j];
    }
    __syncthreads();

    int gid = blockIdx.x * 256 + threadIdx.x;
    int seg = gid / 32;
    int j   = gid % 32;
    if (seg >= nd + no) return;

    const float* srow;
    const float* Wl;
    float acc;
    float* outp;
    if (seg < nd) {
        srow = dag_sum + (size_t)seg * 32;
        Wl = Wd; acc = 0.f;
        outp = dag_h1 + (size_t)seg * 32 + j;
    } else {
        srow = glob_sum + (size_t)(seg - nd) * 32;
        Wl = Wg; acc = b1[j];
        outp = glob_h1 + (size_t)(seg - nd) * 32 + j;
    }
#pragma unroll
    for (int k = 0; k < 32; k++)
        acc = fmaf(srow[k], Wl[k * 32 + j], acc);
    *outp = acc;
}

// ---------------------------------------------------------------------------
// K3: main MLP + score + per-block online softmax (m, sum(exp)).
// ---------------------------------------------------------------------------
__global__ __launch_bounds__(BLK, 3) void mlp_score_kernel(
    const float* __restrict__ x, const float* __restrict__ emb,
    const float* __restrict__ dag_h1, const float* __restrict__ glob_h1,
    const int* __restrict__ dag_ids, const int* __restrict__ obs_ids,
    const int* __restrict__ mask,
    const float* __restrict__ W1, const float* __restrict__ W2,
    const float* __restrict__ b2, const float* __restrict__ W3,
    const float* __restrict__ b3, const float* __restrict__ W4,
    const float* __restrict__ b4,
    float* __restrict__ scores, float* __restrict__ blk_m,
    double* __restrict__ blk_s, int N)
{
    __shared__ float W1l[37 * 32];
    __shared__ float W2l[32 * 16];
    __shared__ float W3l[16 * 8];
    __shared__ float W4l[8];
    __shared__ float b2l[16];
    __shared__ float b3l[8];
    __shared__ float b4s;

    for (int t = threadIdx.x; t < 37 * 32; t += BLK) W1l[t] = W1[t];
    for (int t = threadIdx.x; t < 32 * 16; t += BLK) W2l[t] = W2[t];
    for (int t = threadIdx.x; t < 16 * 8;  t += BLK) W3l[t] = W3[t];
    if (threadIdx.x < 8)  W4l[threadIdx.x] = W4[threadIdx.x];
    if (threadIdx.x < 16) b2l[threadIdx.x] = b2[threadIdx.x];
    if (threadIdx.x < 8)  b3l[threadIdx.x] = b3[threadIdx.x];
    if (threadIdx.x == 0) b4s = b4[0];
    __syncthreads();

    float m = -INFINITY;
    double ssum = 0.0;
    const int stride = gridDim.x * BLK;

    for (int i = blockIdx.x * BLK + threadIdx.x; i < N; i += stride) {
        const int d  = dag_ids[i];
        const int o  = obs_ids[i];
        const int mk = mask[i];

        // --- layer 1 init from precomputed partials (b1 folded in) ---
        float h1[32];
        const float4* dh = (const float4*)(dag_h1 + (size_t)d * 32);
        const float4* gh = (const float4*)(glob_h1 + (size_t)o * 32);
#pragma unroll
        for (int q = 0; q < 8; q++) {
            float4 a = dh[q], b = gh[q];
            h1[4 * q + 0] = a.x + b.x;
            h1[4 * q + 1] = a.y + b.y;
            h1[4 * q + 2] = a.z + b.z;
            h1[4 * q + 3] = a.w + b.w;
        }

        const float* xr = x + (size_t)i * 5;
#pragma unroll
        for (int k = 0; k < 5; k++) {
            float v = xr[k];
#pragma unroll
            for (int j = 0; j < 32; j++)
                h1[j] = fmaf(v, W1l[k * 32 + j], h1[j]);
        }

        const float4* er = (const float4*)(emb + (size_t)i * 32);
#pragma unroll
        for (int q = 0; q < 8; q++) {
            float4 e = er[q];
            float ev[4] = { e.x, e.y, e.z, e.w };
#pragma unroll
            for (int kk = 0; kk < 4; kk++) {
                float v = ev[kk];
                const int k = 5 + q * 4 + kk;
#pragma unroll
                for (int j = 0; j < 32; j++)
                    h1[j] = fmaf(v, W1l[k * 32 + j], h1[j]);
            }
        }
#pragma unroll
        for (int j = 0; j < 32; j++) h1[j] = fmaxf(h1[j], 0.f);

        // --- layer 2 ---
        float h2[16];
#pragma unroll
        for (int j = 0; j < 16; j++) h2[j] = b2l[j];
#pragma unroll
        for (int k = 0; k < 32; k++) {
            float v = h1[k];
#pragma unroll
            for (int j = 0; j < 16; j++)
                h2[j] = fmaf(v, W2l[k * 16 + j], h2[j]);
        }
#pragma unroll
        for (int j = 0; j < 16; j++) h2[j] = fmaxf(h2[j], 0.f);

        // --- layer 3 ---
        float h3[8];
#pragma unroll
        for (int j = 0; j < 8; j++) h3[j] = b3l[j];
#pragma unroll
        for (int k = 0; k < 16; k++) {
            float v = h2[k];
#pragma unroll
            for (int j = 0; j < 8; j++)
                h3[j] = fmaf(v, W3l[k * 8 + j], h3[j]);
        }
#pragma unroll
        for (int j = 0; j < 8; j++) h3[j] = fmaxf(h3[j], 0.f);

        // --- layer 4 ---
        float s = b4s;
#pragma unroll
        for (int k = 0; k < 8; k++) s = fmaf(h3[k], W4l[k], s);

        const bool live = (mk != 0);
        scores[i] = live ? s : -FLT_MAX;
        if (live) {
            if (s > m) {               // first time: expf(-inf)=0 clears nothing
                ssum *= (double)expf(m - s);
                m = s;
            }
            ssum += (double)expf(s - m);
        }
    }

    // --- block (m, sum) merge ---
    __shared__ float  mred[BLK];
    __shared__ double sred[BLK];
    mred[threadIdx.x] = m;
    sred[threadIdx.x] = ssum;
    __syncthreads();
    for (int off = BLK / 2; off > 0; off >>= 1) {
        if (threadIdx.x < off) {
            float ma = mred[threadIdx.x], mb = mred[threadIdx.x + off];
            double sa = sred[threadIdx.x], sb = sred[threadIdx.x + off];
            float M = fmaxf(ma, mb);
            double out = 0.0;
            if (ma > -INFINITY) out += sa * (double)expf(ma - M);
            if (mb > -INFINITY) out += sb * (double)expf(mb - M);
            mred[threadIdx.x] = M;
            sred[threadIdx.x] = out;
        }
        __syncthreads();
    }
    if (threadIdx.x == 0) {
        blk_m[blockIdx.x] = mred[0];
        blk_s[blockIdx.x] = sred[0];
    }
}

// ---------------------------------------------------------------------------
// K4: merge per-block (m, s) pairs -> gmax, Z. One block.
// ---------------------------------------------------------------------------
__global__ __launch_bounds__(1024) void merge_kernel(
    const float* __restrict__ bm, const double* __restrict__ bs, int n,
    float* __restrict__ gmax, double* __restrict__ Z)
{
    float m = -INFINITY;
    double s = 0.0;
    for (int i = threadIdx.x; i < n; i += 1024) {
        float mb = bm[i]; double sb = bs[i];
        float M = fmaxf(m, mb);
        double out = 0.0;
        if (m  > -INFINITY) out += s  * (double)expf(m  - M);
        if (mb > -INFINITY) out += sb * (double)expf(mb - M);
        m = M; s = out;
    }
    __shared__ float  mred[1024];
    __shared__ double sred[1024];
    mred[threadIdx.x] = m;
    sred[threadIdx.x] = s;
    __syncthreads();
    for (int off = 512; off > 0; off >>= 1) {
        if (threadIdx.x < off) {
            float ma = mred[threadIdx.x], mb = mred[threadIdx.x + off];
            double sa = sred[threadIdx.x], sb = sred[threadIdx.x + off];
            float M = fmaxf(ma, mb);
            double out = 0.0;
            if (ma > -INFINITY) out += sa * (double)expf(ma - M);
            if (mb > -INFINITY) out += sb * (double)expf(mb - M);
            mred[threadIdx.x] = M;
            sred[threadIdx.x] = out;
        }
        __syncthreads();
    }
    if (threadIdx.x == 0) { *gmax = mred[0]; *Z = sred[0]; }
}

// ---------------------------------------------------------------------------
// K5: finalize out[i] = exp(s - gmax) / Z  (masked -FLT_MAX -> exactly 0).
// ---------------------------------------------------------------------------
__global__ __launch_bounds__(BLK) void finalize_kernel(
    const float* __restrict__ scores, int N,
    const float* __restrict__ gmaxp, const double* __restrict__ Zp,
    float* __restrict__ outp)
{
    const float gm = *gmaxp;
    const float rZ = (float)(1.0 / *Zp);
    int i = blockIdx.x * BLK + threadIdx.x;
    if (i < N) outp[i] = expf(scores[i] - gm) * rZ;
}

// ---------------------------------------------------------------------------
extern "C" void kernel_launch(void* const* d_in, const int* in_sizes, int n_in,
                              void* d_out, int out_size, void* d_ws, size_t ws_size,
                              hipStream_t stream)
{
    const float* x        = (const float*)d_in[0];
    const float* emb      = (const float*)d_in[1];
    const float* dag_sum  = (const float*)d_in[2];
    const float* glob_sum = (const float*)d_in[3];
    const int*   dag_cnt  = (const int*)d_in[4];
    const int*   obs_cnt  = (const int*)d_in[5];
    const int*   mask     = (const int*)d_in[6];   // bool staged as int32
    const float* W1 = (const float*)d_in[7];
    const float* b1 = (const float*)d_in[8];
    const float* W2 = (const float*)d_in[9];
    const float* b2 = (const float*)d_in[10];
    const float* W3 = (const float*)d_in[11];
    const float* b3 = (const float*)d_in[12];
    const float* W4 = (const float*)d_in[13];
    const float* b4 = (const float*)d_in[14];
    float* outp = (float*)d_out;

    const int N  = in_sizes[0] / 5;   // 2,000,000
    const int nd = in_sizes[4];       // 20,000
    const int no = in_sizes[5];       // 1,000

    // --- workspace layout (16B aligned slices) ---
    char* ws = (char*)d_ws;
    size_t off = 0;
    auto alloc = [&](size_t bytes) {
        void* p = ws + off;
        off += (bytes + 15) & ~(size_t)15;
        return p;
    };
    int*    dag_starts = (int*)   alloc((size_t)(nd + 1) * sizeof(int));
    int*    obs_starts = (int*)   alloc((size_t)(no + 1) * sizeof(int));
    int*    dag_ids    = (int*)   alloc((size_t)N * sizeof(int));
    int*    obs_ids    = (int*)   alloc((size_t)N * sizeof(int));
    float*  dag_h1     = (float*) alloc((size_t)nd * 32 * sizeof(float));
    float*  glob_h1    = (float*) alloc((size_t)no * 32 * sizeof(float));
    float*  scores     = (float*) alloc((size_t)N * sizeof(float));
    float*  blk_m      = (float*) alloc((size_t)MAIN_BLOCKS * sizeof(float));
    double* blk_s      = (double*)alloc((size_t)MAIN_BLOCKS * sizeof(double));
    float*  gmax       = (float*) alloc(sizeof(float));
    double* Z          = (double*)alloc(sizeof(double));
    (void)ws_size;

    // K0: prefix scans (fast single-pass)
    scan2_kernel<<<1, 1024, 0, stream>>>(dag_cnt, nd, obs_cnt, no, dag_starts, obs_starts);

    // K1: expand segment ids to nodes
    expand_ids_kernel<<<nd + no, 128, 0, stream>>>(dag_starts, nd, obs_starts, no, dag_ids, obs_ids);

    // K2: per-segment layer-1 partials
    {
        int total = (nd + no) * 32;
        seg_h1_kernel<<<(total + 255) / 256, 256, 0, stream>>>(
            dag_sum, nd, glob_sum, no, W1, b1, dag_h1, glob_h1);
    }

    // K3: main MLP + scores + per-block online softmax
    mlp_score_kernel<<<MAIN_BLOCKS, BLK, 0, stream>>>(
        x, emb, dag_h1, glob_h1, dag_ids, obs_ids, mask,
        W1, W2, b2, W3, b3, W4, b4, scores, blk_m, blk_s, N);

    // K4: merge -> gmax, Z
    merge_kernel<<<1, 1024, 0, stream>>>(blk_m, blk_s, MAIN_BLOCKS, gmax, Z);

    // K5: finalize
    finalize_kernel<<<(N + BLK - 1) / BLK, BLK, 0, stream>>>(scores, N, gmax, Z, outp);
}